// Round 11
// baseline (203.770 us; speedup 1.0000x reference)
//
#include <hip/hip_runtime.h>
#include <math.h>
#include <string.h>
#include <stdint.h>

#define N_STFT 1025
#define N_MELS 128
#define BATCH 4
#define TIME 1024
#define MAX_ITER 20

typedef unsigned int u32;
typedef unsigned long long u64;

// Native LDS f32 atomic add. Plain atomicAdd(float*) on LDS compiles to a
// ds_cmpst CAS loop (denormal-flush semantics gate ds_add_f32 behind
// -munsafe-fp-atomics, which the harness doesn't pass) — that CAS was the
// r11-r14 3x regression. Inline asm emits the single native op. The LDS byte
// offset is the low 32 bits of the generic pointer (shared aperture is 4GiB
// aligned on AMDGCN, so truncation = AS3 offset). Denormal flush is
// irrelevant (P values O(1..100)).
__device__ __forceinline__ void lds_fadd(u32 byte_off, float v) {
  asm volatile("ds_add_f32 %0, %1" :: "v"(byte_off), "v"(v) : "memory");
}
__device__ __forceinline__ void lds_fadd_off4(u32 byte_off, float v) {
  asm volatile("ds_add_f32 %0, %1 offset:4" :: "v"(byte_off), "v"(v) : "memory");
}

// r19 (resubmit — round-10 bench was a container/infra failure, same
// signature as round 1 which succeeded verbatim on retry):
// kill the fixed-point machinery, keep everything else = r6 champion.
// Ledger conclusion from r15-r18: SQ_LDS_BANK_CONFLICT ~= (bank_cycles -
// issues) of the DS op mix (r6's 71cy/wave-iter == 16 read2 x3 + 17 atomic
// x1 + writes x2) — irreducible, swizzle-invariant, not same-address RMW.
// DS mix is near-minimal. The largest remaining block is VALU: ~375
// instr/wave-iter, of which ~82 are fixed-point cvts (rndne+cvt per atomic,
// u32->f32 per read, INV48 scaling) that exist ONLY because f32 atomicAdd
// CAS-loops. Native ds_add_f32 (asm above) removes all of it: P is f32,
// weights unscaled, g = fma(p0,w0, fma(p1,w1, cc)), buf' domain (r11-proven
// numerics, passed 4x with identical absmax). Zero phase: one ds_write_b64.
__global__ __launch_bounds__(256)
__attribute__((amdgpu_waves_per_eu(2, 4))) void imel_main(
    const float* __restrict__ melspec, const float* __restrict__ spec_init,
    const int* __restrict__ m0f, const float* __restrict__ w0a,
    const float* __restrict__ w1a, float* __restrict__ out) {
  __shared__ float s_P[4][N_MELS];   // per-wave private P row (f32)
  __shared__ float s_mel[4][N_MELS]; // staged mel columns (prologue only)
  __shared__ float s_out[4][1060];   // swizzle-padded: idx = f + (f>>5)

  const int tid = threadIdx.x;
  const int w   = tid >> 6;        // wave 0..3 -> row t0+w
  const int l   = tid & 63;
  // XCD swizzle for grid 1024: XCD x covers flats [x*128, x*128+128) = one
  // contiguous quarter-batch t-range -> melspec slice L2-resident and
  // adjacent blocks (adjacent t0, same XCD) merge 16B output granules in L2.
  const int flat = (blockIdx.x & 7) * 128 + (blockIdx.x >> 3);
  const int b   = flat >> 8;          // 256 flats per batch
  const int t0  = (flat & 255) << 2;  // block covers t0..t0+3
  const int tA  = t0 + w;

  // ---- stage mel columns: s_mel[r][m] = mel[b][m][t0+r] ----
  for (int i = tid; i < 4 * N_MELS; i += 256) {
    const int m = i >> 2, r = i & 3;
    s_mel[r][m] = melspec[((size_t)b * N_MELS + m) * TIME + t0 + r];
  }
  __syncthreads();

  // LR * inv = 0.3 * 2/(B*T): applied at the spec update (buf' domain)
  const float LRI = 0.3f * (2.0f / (BATCH * TIME)); // 1.46484375e-4f

  // per-lane static structure, f = 16*l + k  (f=1024: zero fb row -> copy)
  float rs[16], rb[16], rw0[16], rw1[16], cc[16];
  int rm[16];

  const float* srow = spec_init + (size_t)(b * TIME + tA) * N_STFT;
  const float* melW = &s_mel[w][0];
#pragma unroll
  for (int k = 0; k < 16; ++k) {
    const int f = (l << 4) + k;
    rs[k] = srow[f];
    const int m = m0f[f];
    rm[k] = m;
    const float w0 = w0a[f], w1 = w1a[f];
    rw0[k] = w0;
    rw1[k] = w1;
    cc[k] = -fmaf(melW[m], w0, melW[m + 1] * w1);  // -(mel.w), buf' domain
    rb[k] = 0.f;
  }
  const float rt = (l == 63) ? srow[1024] : 0.f;

  float* __restrict__ Pw = &s_P[w][0];
  const u32 pbase = (u32)(uintptr_t)Pw;   // LDS byte offset of this wave's P
  {
    u64* Pz = (u64*)Pw;
    Pz[l] = 0ULL;                         // one ds_write_b64: floats 2l,2l+1
  }
  // wave-private P: no block barrier anywhere in the hot loop

  for (int it = 0; it < MAX_ITER; ++it) {
    // ---- forward: run-compacted scatter (native ds_add_f32) ----
    {
      float a0 = rs[0] * rw0[0], a1 = rs[0] * rw1[0];
#pragma unroll
      for (int k = 1; k < 16; ++k) {
        const bool adv = (rm[k] != rm[k - 1]);  // m0 monotone, step <= 1/bin
        if (adv) lds_fadd(pbase + (u32)(rm[k - 1] << 2), a0);
        const float n0 = (adv ? a1 : a0) + rs[k] * rw0[k];
        a1 = (adv ? 0.f : a1) + rs[k] * rw1[k];
        a0 = n0;
      }
      const u32 fin = pbase + (u32)(rm[15] << 2);
      lds_fadd(fin, a0);
      lds_fadd_off4(fin, a1);
    }
    __builtin_amdgcn_wave_barrier();   // scheduling fence only
    // ---- backward: unconditional ds_read2_b32 per k, all k independent ----
#pragma unroll
    for (int k = 0; k < 16; ++k) {
      const float p0 = Pw[rm[k]];        // pairs into ds_read2_b32
      const float p1 = Pw[rm[k] + 1];
      const float g  = fmaf(p0, rw0[k], fmaf(p1, rw1[k], cc[k]));
      rb[k] = fmaf(0.9f, rb[k], g);
      rs[k] = fmaxf(fmaf(-LRI, rb[k], rs[k]), 0.f);
    }
    __builtin_amdgcn_wave_barrier();
    // ---- zero P for next iteration (same-wave DS program order) ----
    {
      u64* Pz = (u64*)Pw;
      Pz[l] = 0ULL;
    }
    __builtin_amdgcn_wave_barrier();
  }

  // ---- epilogue: transpose (f-major regs) -> (B, F, T) via swizzled LDS ----
#pragma unroll
  for (int k = 0; k < 16; ++k) {
    const int f = (l << 4) + k;
    s_out[w][f + (f >> 5)] = rs[k];
  }
  if (l == 63) s_out[w][1056] = rt;    // f=1024 -> 1024 + (1024>>5)
  __syncthreads();

  const int tl = tid & 3;    // t offset within the block's 4 rows
  const int fg = tid >> 2;   // 64 f phases
  float* obase = out + (size_t)b * N_STFT * TIME + t0 + tl;
  for (int f = fg; f < N_STFT; f += 64) {
    obase[(size_t)f * TIME] = s_out[tl][f + (f >> 5)];
  }
}

// ---------------- host-side fb structure (replaces imel_prep) -------------
// Same math as the reference's _create_fb_matrix, f64 throughout, f32 cast
// at the end. fb[f][m] > 0  <=>  f_pts[m] < freq(f) < f_pts[m+2].
static unsigned char g_tab[15360];
static bool g_tab_ready = false;

static float host_fbval(double freq, const double* f_pts, int m) {
  const double down = (freq - f_pts[m]) / (f_pts[m + 1] - f_pts[m]);
  const double up = (f_pts[m + 2] - freq) / (f_pts[m + 2] - f_pts[m + 1]);
  double v = down < up ? down : up;
  if (v < 0.0) v = 0.0;
  return (float)v;
}

static void build_tab() {
  double f_pts[130];
  const double m_max = 2595.0 * log10(1.0 + 8000.0 / 700.0);
  for (int i = 0; i < 130; ++i) {
    const double m = (double)i * m_max / 129.0;   // linspace(0, m_max, 130)
    f_pts[i] = 700.0 * (pow(10.0, m / 2595.0) - 1.0);
  }
  int* m0f = (int*)g_tab;
  float* w0a = (float*)(g_tab + 5120);
  float* w1a = (float*)(g_tab + 10240);
  for (int f = 0; f < N_STFT; ++f) {
    const double freq = (double)f * (8000.0 / 1024.0);
    int m0 = 0;                      // all-zero rows (f=0, f=1024) -> 0
    for (int m = 0; m < N_MELS; ++m) {
      if (host_fbval(freq, f_pts, m) != 0.0f) { m0 = m; break; }
    }
    if (m0 > N_MELS - 2) m0 = N_MELS - 2;  // keep (m0, m0+1) in range
    m0f[f] = m0;
    w0a[f] = host_fbval(freq, f_pts, m0);
    w1a[f] = host_fbval(freq, f_pts, m0 + 1);
  }
}

extern "C" void kernel_launch(void* const* d_in, const int* in_sizes, int n_in,
                              void* d_out, int out_size, void* d_ws, size_t ws_size,
                              hipStream_t stream) {
  const float* melspec = (const float*)d_in[0];
  const float* spec_init = (const float*)d_in[1];
  float* out = (float*)d_out;

  if (!g_tab_ready) { build_tab(); g_tab_ready = true; }

  int* m0f = (int*)d_ws;                          // 1025 ints
  float* w0a = (float*)((char*)d_ws + 5120);      // 1025 floats
  float* w1a = (float*)((char*)d_ws + 10240);     // 1025 floats

  hipMemcpyAsync(d_ws, g_tab, sizeof(g_tab), hipMemcpyHostToDevice, stream);
  imel_main<<<dim3(1024), dim3(256), 0, stream>>>(melspec, spec_init, m0f, w0a, w1a, out);
}

// Round 12
// 135.241 us; speedup vs baseline: 1.5067x; 1.5067x over previous
//
#include <hip/hip_runtime.h>
#include <math.h>
#include <stdint.h>

#define N_STFT 1025
#define N_MELS 128
#define BATCH 4
#define TIME 1024
#define MAX_ITER 20

typedef unsigned int u32;
typedef unsigned long long u64;

// r20 = r18 champion (49.2us, u32 fixed-point ds_add_u32) + run-deduped
// backward gather + INV48 fold. Ledger updates:
// - r19 DISPROVED the CAS theory: asm-native ds_add_f32 reproduced r13/r14
//   exactly (134us, conflicts bit-identical 4,997,120) -> hipcc was emitting
//   native ds_add_f32 all along; the f32 LDS atomic RMW pipe is itself ~3x
//   slower than ds_add_u32. Integer fixed-point is the right design.
// - r18 budget: VALU ~25us/SIMD (51%, ~375 instr/wave-iter), DS ~22us/CU,
//   wall 49 = poor overlap. Biggest DS item: 16 unpredicated ds_read2_b32
//   (64 base + ~48 extra bank-cy/iter), mostly DUPLICATE reads (m0 advances
//   ~2x/lane avg; r16 A/B proved predicated beats unpredicated for atomics).
// This round: backward reads the P pair only on advance (predicated, ~12
// active lanes/issue) into fresh temps + 2 cndmask/k propagation. Reads stay
// pipelined (distinct dests). INV48 folded: cc in 2^48 domain, LRI48
// (r16-validated numerics). Expected DS/CU 22->~11us.
__global__ __launch_bounds__(256)
__attribute__((amdgpu_waves_per_eu(2, 4))) void imel_main(
    const float* __restrict__ melspec, const float* __restrict__ spec_init,
    const int* __restrict__ m0f, const float* __restrict__ w0a,
    const float* __restrict__ w1a, float* __restrict__ out) {
  __shared__ u32   s_P[4][N_MELS];   // per-wave private P row (u32 fixed pt)
  __shared__ float s_mel[4][N_MELS]; // staged mel columns (prologue only)
  __shared__ float s_out[4][1060];   // swizzle-padded: idx = f + (f>>5)

  const int tid = threadIdx.x;
  const int w   = tid >> 6;        // wave 0..3 -> row t0+w
  const int l   = tid & 63;
  // XCD swizzle for grid 1024: XCD x covers flats [x*128, x*128+128) = one
  // contiguous quarter-batch t-range -> melspec slice L2-resident and
  // adjacent blocks (adjacent t0, same XCD) merge 16B output granules in L2.
  const int flat = (blockIdx.x & 7) * 128 + (blockIdx.x >> 3);
  const int b   = flat >> 8;          // 256 flats per batch
  const int t0  = (flat & 255) << 2;  // block covers t0..t0+3
  const int tA  = t0 + w;

  // ---- stage mel columns: s_mel[r][m] = mel[b][m][t0+r] ----
  for (int i = tid; i < 4 * N_MELS; i += 256) {
    const int m = i >> 2, r = i & 3;
    s_mel[r][m] = melspec[((size_t)b * N_MELS + m) * TIME + t0 + r];
  }
  __syncthreads();

  const float SCALE = 16777216.0f;                 // 2^24 fixed point
  const float SC48  = 281474976710656.0f;          // 2^48 (cc domain)
  // LR * inv * 2^-48: spec -= LRI48 * rb  (rb is 2^48-scaled buf'/inv)
  const float LRI48 = 5.2041704279304213e-19f;     // 0.3*2/(B*T) * 2^-48

  // per-lane static structure, f = 16*l + k  (f=1024: zero fb row -> copy)
  float rs[16], rb[16], rw0[16], rw1[16], cc[16];
  int rm[16];

  const float* srow = spec_init + (size_t)(b * TIME + tA) * N_STFT;
  const float* melW = &s_mel[w][0];
#pragma unroll
  for (int k = 0; k < 16; ++k) {
    const int f = (l << 4) + k;
    rs[k] = srow[f];
    const int m = m0f[f];
    rm[k] = m;
    const float w0 = w0a[f], w1 = w1a[f];
    rw0[k] = w0 * SCALE;
    rw1[k] = w1 * SCALE;
    cc[k] = -SC48 * fmaf(melW[m], w0, melW[m + 1] * w1);  // -(mel.w)*2^48
    rb[k] = 0.f;
  }
  const float rt = (l == 63) ? srow[1024] : 0.f;

  // loop-invariant advance flags (m0 monotone, step <= 1 per bin) ->
  // hoisted v_cmp, masks live in SGPRs across the whole hot loop
  bool adv[16];
  adv[0] = false;
#pragma unroll
  for (int k = 1; k < 16; ++k) adv[k] = (rm[k] != rm[k - 1]);

  u32* __restrict__ Pw = &s_P[w][0];
  ((u64*)Pw)[l] = 0ULL;              // one ds_write_b64 zeroes 2 bins/lane
  // wave-private P: no block barrier anywhere in the hot loop

  for (int it = 0; it < MAX_ITER; ++it) {
    // ---- forward: run-compacted scatter (native ds_add_u32) ----
    {
      float a0 = rs[0] * rw0[0], a1 = rs[0] * rw1[0];
#pragma unroll
      for (int k = 1; k < 16; ++k) {
        if (adv[k]) atomicAdd(&Pw[rm[k - 1]], (u32)__float2int_rn(a0));
        const float n0 = (adv[k] ? a1 : a0) + rs[k] * rw0[k];
        a1 = (adv[k] ? 0.f : a1) + rs[k] * rw1[k];
        a0 = n0;
      }
      atomicAdd(&Pw[rm[15]],     (u32)__float2int_rn(a0));
      atomicAdd(&Pw[rm[15] + 1], (u32)__float2int_rn(a1));
    }
    __builtin_amdgcn_wave_barrier();   // scheduling fence only
    // ---- backward: run-deduped gather — read P pair only on advance
    //      (predicated ds_read, ~12 active lanes/issue), cndmask propagate.
    //      Reads pipeline (distinct dests); only the merge waits. ----
    {
      float p0 = (float)(int)Pw[rm[0]];
      float p1 = (float)(int)Pw[rm[0] + 1];
      {
        const float g = fmaf(p1, rw1[0], fmaf(p0, rw0[0], cc[0]));
        rb[0] = fmaf(0.9f, rb[0], g);
        rs[0] = fmaxf(fmaf(-LRI48, rb[0], rs[0]), 0.f);
      }
#pragma unroll
      for (int k = 1; k < 16; ++k) {
        float f0 = p0, f1 = p1;
        if (adv[k]) {
          f0 = (float)(int)Pw[rm[k]];
          f1 = (float)(int)Pw[rm[k] + 1];
        }
        p0 = f0;
        p1 = f1;
        const float g = fmaf(p1, rw1[k], fmaf(p0, rw0[k], cc[k]));
        rb[k] = fmaf(0.9f, rb[k], g);
        rs[k] = fmaxf(fmaf(-LRI48, rb[k], rs[k]), 0.f);
      }
    }
    __builtin_amdgcn_wave_barrier();
    // ---- zero P for next iteration (same-wave DS program order) ----
    ((u64*)Pw)[l] = 0ULL;
    __builtin_amdgcn_wave_barrier();
  }

  // ---- epilogue: transpose (f-major regs) -> (B, F, T) via swizzled LDS ----
#pragma unroll
  for (int k = 0; k < 16; ++k) {
    const int f = (l << 4) + k;
    s_out[w][f + (f >> 5)] = rs[k];
  }
  if (l == 63) s_out[w][1056] = rt;    // f=1024 -> 1024 + (1024>>5)
  __syncthreads();

  const int tl = tid & 3;    // t offset within the block's 4 rows
  const int fg = tid >> 2;   // 64 f phases
  float* obase = out + (size_t)b * N_STFT * TIME + t0 + tl;
  for (int f = fg; f < N_STFT; f += 64) {
    obase[(size_t)f * TIME] = s_out[tl][f + (f >> 5)];
  }
}

// ---------------- host-side fb structure (replaces imel_prep) -------------
// Same math as the reference's _create_fb_matrix, f64 throughout, f32 cast
// at the end. fb[f][m] > 0  <=>  f_pts[m] < freq(f) < f_pts[m+2].
static unsigned char g_tab[15360];
static bool g_tab_ready = false;

static float host_fbval(double freq, const double* f_pts, int m) {
  const double down = (freq - f_pts[m]) / (f_pts[m + 1] - f_pts[m]);
  const double up = (f_pts[m + 2] - freq) / (f_pts[m + 2] - f_pts[m + 1]);
  double v = down < up ? down : up;
  if (v < 0.0) v = 0.0;
  return (float)v;
}

static void build_tab() {
  double f_pts[130];
  const double m_max = 2595.0 * log10(1.0 + 8000.0 / 700.0);
  for (int i = 0; i < 130; ++i) {
    const double m = (double)i * m_max / 129.0;   // linspace(0, m_max, 130)
    f_pts[i] = 700.0 * (pow(10.0, m / 2595.0) - 1.0);
  }
  int* m0f = (int*)g_tab;
  float* w0a = (float*)(g_tab + 5120);
  float* w1a = (float*)(g_tab + 10240);
  for (int f = 0; f < N_STFT; ++f) {
    const double freq = (double)f * (8000.0 / 1024.0);
    int m0 = 0;                      // all-zero rows (f=0, f=1024) -> 0
    for (int m = 0; m < N_MELS; ++m) {
      if (host_fbval(freq, f_pts, m) != 0.0f) { m0 = m; break; }
    }
    if (m0 > N_MELS - 2) m0 = N_MELS - 2;  // keep (m0, m0+1) in range
    m0f[f] = m0;
    w0a[f] = host_fbval(freq, f_pts, m0);
    w1a[f] = host_fbval(freq, f_pts, m0 + 1);
  }
}

extern "C" void kernel_launch(void* const* d_in, const int* in_sizes, int n_in,
                              void* d_out, int out_size, void* d_ws, size_t ws_size,
                              hipStream_t stream) {
  const float* melspec = (const float*)d_in[0];
  const float* spec_init = (const float*)d_in[1];
  float* out = (float*)d_out;

  if (!g_tab_ready) { build_tab(); g_tab_ready = true; }

  int* m0f = (int*)d_ws;                          // 1025 ints
  float* w0a = (float*)((char*)d_ws + 5120);      // 1025 floats
  float* w1a = (float*)((char*)d_ws + 10240);     // 1025 floats

  hipMemcpyAsync(d_ws, g_tab, sizeof(g_tab), hipMemcpyHostToDevice, stream);
  imel_main<<<dim3(1024), dim3(256), 0, stream>>>(melspec, spec_init, m0f, w0a, w1a, out);
}

// Round 13
// 124.914 us; speedup vs baseline: 1.6313x; 1.0827x over previous
//
#include <hip/hip_runtime.h>
#include <math.h>
#include <stdint.h>

#define N_STFT 1025
#define N_MELS 128
#define BATCH 4
#define TIME 1024
#define MAX_ITER 20

typedef unsigned int u32;
typedef unsigned long long u64;

// r21 = r18 champion (49.2us) restructured for within-wave pipe overlap.
// Ledger: r20 proved serial-dependent DS reads are poison (conflicts -62%
// but dur +35% from 16 sequential lgkmcnt waits) -> keep UNPREDICATED
// independent read2s. r18 budget: VALU ~25us/SIMD + DS ~20us/CU ~= wall 49
// -> phases serialize at waitcnt boundaries; pipes don't overlap in-wave.
// Fix: double-buffered P. fused(it) = backward(it) reading P_a INTERLEAVED
// with forward(it+1) scattering P_b (zero aliasing -> reads, momentum math,
// and the serial a0/a1 chain share one scheduling region; reads hide under
// chain FMA latency and vice versa). zero(P_a) after each fused; buffers
// swap. Same DS op count, same arithmetic values (scatter order per bin
// unchanged) -> absmax bit-identical. Schedule: F0; 9x(fused P0->P1,
// fused P1->P0); fused_18; B19 = 20 fwd + 20 bwd.
// Numerics (all validated passing): u32 fixed-point P (2^24), trunc(x+0.5)
// rounding (operands >= 0), cc in 2^48 domain, LRI48 fold.
__global__ __launch_bounds__(256)
__attribute__((amdgpu_waves_per_eu(2, 4))) void imel_main(
    const float* __restrict__ melspec, const float* __restrict__ spec_init,
    const int* __restrict__ m0f, const float* __restrict__ w0a,
    const float* __restrict__ w1a, float* __restrict__ out) {
  __shared__ u32   s_P[4][2][N_MELS]; // per-wave DOUBLE-BUFFERED P (u32 fx)
  __shared__ float s_mel[4][N_MELS];  // staged mel columns (prologue only)
  __shared__ float s_out[4][1060];    // swizzle-padded: idx = f + (f>>5)

  const int tid = threadIdx.x;
  const int w   = tid >> 6;        // wave 0..3 -> row t0+w
  const int l   = tid & 63;
  // XCD swizzle for grid 1024: XCD x covers flats [x*128, x*128+128) -> L2
  // locality for melspec slice + adjacent output granules merge in L2.
  const int flat = (blockIdx.x & 7) * 128 + (blockIdx.x >> 3);
  const int b   = flat >> 8;          // 256 flats per batch
  const int t0  = (flat & 255) << 2;  // block covers t0..t0+3
  const int tA  = t0 + w;

  // ---- stage mel columns: s_mel[r][m] = mel[b][m][t0+r] ----
  for (int i = tid; i < 4 * N_MELS; i += 256) {
    const int m = i >> 2, r = i & 3;
    s_mel[r][m] = melspec[((size_t)b * N_MELS + m) * TIME + t0 + r];
  }
  __syncthreads();

  const float SCALE = 16777216.0f;                 // 2^24 fixed point
  const float SC48  = 281474976710656.0f;          // 2^48 (cc domain)
  const float LRI48 = 5.2041704279304213e-19f;     // 0.3*2/(B*T) * 2^-48

  // per-lane static structure, f = 16*l + k  (f=1024: zero fb row -> copy)
  float rs[16], rb[16], rw0[16], rw1[16], cc[16];
  int rm[16];

  const float* srow = spec_init + (size_t)(b * TIME + tA) * N_STFT;
  const float* melW = &s_mel[w][0];
#pragma unroll
  for (int k = 0; k < 16; ++k) {
    const int f = (l << 4) + k;
    rs[k] = srow[f];
    const int m = m0f[f];
    rm[k] = m;
    const float w0 = w0a[f], w1 = w1a[f];
    rw0[k] = w0 * SCALE;
    rw1[k] = w1 * SCALE;
    cc[k] = -SC48 * fmaf(melW[m], w0, melW[m + 1] * w1);  // -(mel.w)*2^48
    rb[k] = 0.f;
  }
  const float rt = (l == 63) ? srow[1024] : 0.f;

  // loop-invariant advance flags (m0 monotone, step <= 1 per bin)
  bool adv[16];
  adv[0] = false;
#pragma unroll
  for (int k = 1; k < 16; ++k) adv[k] = (rm[k] != rm[k - 1]);

  u32* __restrict__ P0 = &s_P[w][0][0];
  u32* __restrict__ P1 = &s_P[w][1][0];
  {  // zero BOTH buffers (contiguous 1KB): 2 x ds_write_b64 per lane
    u64* Z = (u64*)P0;
    Z[l] = 0ULL;
    Z[l + 64] = 0ULL;
  }
  // wave-private P: no block barrier anywhere in the hot loop

  auto wb = [] { __builtin_amdgcn_wave_barrier(); };

  // forward-only: scatter current rs into Pb (run-compacted, ds_add_u32)
  auto fwd = [&](u32* __restrict__ Pb) {
    float a0 = rs[0] * rw0[0], a1 = rs[0] * rw1[0];
#pragma unroll
    for (int k = 1; k < 16; ++k) {
      if (adv[k]) atomicAdd(&Pb[rm[k - 1]], (u32)(a0 + 0.5f));
      const float n0 = (adv[k] ? a1 : a0) + rs[k] * rw0[k];
      a1 = (adv[k] ? 0.f : a1) + rs[k] * rw1[k];
      a0 = n0;
    }
    atomicAdd(&Pb[rm[15]],     (u32)(a0 + 0.5f));
    atomicAdd(&Pb[rm[15] + 1], (u32)(a1 + 0.5f));
  };

  // fused: backward(it) from Pa interleaved with forward(it+1) into Pb.
  // Reads unpredicated + independent (r20 lesson); chain is the only
  // serial thread and hides under read latency.
  auto fused = [&](const u32* __restrict__ Pa, u32* __restrict__ Pb) {
    float a0 = 0.f, a1 = 0.f;
#pragma unroll
    for (int k = 0; k < 16; ++k) {
      const float p0 = (float)(int)Pa[rm[k]];      // ds_read2_b32 pair
      const float p1 = (float)(int)Pa[rm[k] + 1];
      const float g  = fmaf(p1, rw1[k], fmaf(p0, rw0[k], cc[k]));
      rb[k] = fmaf(0.9f, rb[k], g);
      rs[k] = fmaxf(fmaf(-LRI48, rb[k], rs[k]), 0.f);
      if (k == 0) {
        a0 = rs[0] * rw0[0];
        a1 = rs[0] * rw1[0];
      } else {
        if (adv[k]) atomicAdd(&Pb[rm[k - 1]], (u32)(a0 + 0.5f));
        const float n0 = (adv[k] ? a1 : a0) + rs[k] * rw0[k];
        a1 = (adv[k] ? 0.f : a1) + rs[k] * rw1[k];
        a0 = n0;
      }
    }
    atomicAdd(&Pb[rm[15]],     (u32)(a0 + 0.5f));
    atomicAdd(&Pb[rm[15] + 1], (u32)(a1 + 0.5f));
  };

  // backward-only (last iteration)
  auto bwd = [&](const u32* __restrict__ Pa) {
#pragma unroll
    for (int k = 0; k < 16; ++k) {
      const float p0 = (float)(int)Pa[rm[k]];
      const float p1 = (float)(int)Pa[rm[k] + 1];
      const float g  = fmaf(p1, rw1[k], fmaf(p0, rw0[k], cc[k]));
      rb[k] = fmaf(0.9f, rb[k], g);
      rs[k] = fmaxf(fmaf(-LRI48, rb[k], rs[k]), 0.f);
    }
  };

  auto zero = [&](u32* __restrict__ P) { ((u64*)P)[l] = 0ULL; };

  fwd(P0);                 // F0 -> P0
  wb();
#pragma unroll 1
  for (int p = 0; p < 9; ++p) {       // fused_0..17 (B0..B17, F1..F18)
    fused(P0, P1); wb(); zero(P0); wb();
    fused(P1, P0); wb(); zero(P1); wb();
  }
  fused(P0, P1);           // fused_18: B18 + F19 -> P1
  wb();
  bwd(P1);                 // B19

  // ---- epilogue: transpose (f-major regs) -> (B, F, T) via swizzled LDS ----
#pragma unroll
  for (int k = 0; k < 16; ++k) {
    const int f = (l << 4) + k;
    s_out[w][f + (f >> 5)] = rs[k];
  }
  if (l == 63) s_out[w][1056] = rt;    // f=1024 -> 1024 + (1024>>5)
  __syncthreads();

  const int tl = tid & 3;    // t offset within the block's 4 rows
  const int fg = tid >> 2;   // 64 f phases
  float* obase = out + (size_t)b * N_STFT * TIME + t0 + tl;
  for (int f = fg; f < N_STFT; f += 64) {
    obase[(size_t)f * TIME] = s_out[tl][f + (f >> 5)];
  }
}

// ---------------- host-side fb structure (replaces imel_prep) -------------
static unsigned char g_tab[15360];
static bool g_tab_ready = false;

static float host_fbval(double freq, const double* f_pts, int m) {
  const double down = (freq - f_pts[m]) / (f_pts[m + 1] - f_pts[m]);
  const double up = (f_pts[m + 2] - freq) / (f_pts[m + 2] - f_pts[m + 1]);
  double v = down < up ? down : up;
  if (v < 0.0) v = 0.0;
  return (float)v;
}

static void build_tab() {
  double f_pts[130];
  const double m_max = 2595.0 * log10(1.0 + 8000.0 / 700.0);
  for (int i = 0; i < 130; ++i) {
    const double m = (double)i * m_max / 129.0;   // linspace(0, m_max, 130)
    f_pts[i] = 700.0 * (pow(10.0, m / 2595.0) - 1.0);
  }
  int* m0f = (int*)g_tab;
  float* w0a = (float*)(g_tab + 5120);
  float* w1a = (float*)(g_tab + 10240);
  for (int f = 0; f < N_STFT; ++f) {
    const double freq = (double)f * (8000.0 / 1024.0);
    int m0 = 0;                      // all-zero rows (f=0, f=1024) -> 0
    for (int m = 0; m < N_MELS; ++m) {
      if (host_fbval(freq, f_pts, m) != 0.0f) { m0 = m; break; }
    }
    if (m0 > N_MELS - 2) m0 = N_MELS - 2;  // keep (m0, m0+1) in range
    m0f[f] = m0;
    w0a[f] = host_fbval(freq, f_pts, m0);
    w1a[f] = host_fbval(freq, f_pts, m0 + 1);
  }
}

extern "C" void kernel_launch(void* const* d_in, const int* in_sizes, int n_in,
                              void* d_out, int out_size, void* d_ws, size_t ws_size,
                              hipStream_t stream) {
  const float* melspec = (const float*)d_in[0];
  const float* spec_init = (const float*)d_in[1];
  float* out = (float*)d_out;

  if (!g_tab_ready) { build_tab(); g_tab_ready = true; }

  int* m0f = (int*)d_ws;                          // 1025 ints
  float* w0a = (float*)((char*)d_ws + 5120);      // 1025 floats
  float* w1a = (float*)((char*)d_ws + 10240);     // 1025 floats

  hipMemcpyAsync(d_ws, g_tab, sizeof(g_tab), hipMemcpyHostToDevice, stream);
  imel_main<<<dim3(1024), dim3(256), 0, stream>>>(melspec, spec_init, m0f, w0a, w1a, out);
}

// Round 14
// 115.884 us; speedup vs baseline: 1.7584x; 1.0779x over previous
//
#include <hip/hip_runtime.h>
#include <math.h>
#include <stdint.h>

#define N_STFT 1025
#define N_MELS 128
#define BATCH 4
#define TIME 1024
#define MAX_ITER 20

typedef unsigned int u32;
typedef unsigned long long u64;

// r22 = r18 champion (49.2us) + wave phase-STAGGER + validated VALU trims.
// Ledger r20/r21: B(it)->F(it+1) are data-dependent per k; any fusion
// rebuilds the serial read-latency chain (r20 66us, r21 56us). Phases must
// stay separate. Budget audit: 375 VALU x2cy + 34 DS ~= 784 issue-cy per
// wave-iter; 4 waves x 20 x 784 = 26us/SIMD = VALUBusy(51%) x wall(49us).
// The other 49%: ZERO waves issuable — the 4 waves/SIMD are wave-w of 4
// co-launched blocks running identical streams in LOCKSTEP: VALU phases
// collide (2x issue oversubscription), DS-wait phases collide (issue idle).
// Fix: one-time ~quarter-iteration stagger (s_sleep(3) x phase, 192cy each,
// phase = ((bid>>3)+w)&3) before the hot loop; offsets persist since per-
// iter duration is identical. Expected: VALU fills others' DS waits.
// Trims (each validated passing, absmax identical): trunc(x+0.5) rounding
// (r16/r21), cc pre-scaled 2^48 + LRI48 fold (r20/r21) — saves ~33 VALU/iter.
__global__ __launch_bounds__(256)
__attribute__((amdgpu_waves_per_eu(2, 4))) void imel_main(
    const float* __restrict__ melspec, const float* __restrict__ spec_init,
    const int* __restrict__ m0f, const float* __restrict__ w0a,
    const float* __restrict__ w1a, float* __restrict__ out) {
  __shared__ u32   s_P[4][N_MELS];   // per-wave private P row (u32 fixed pt)
  __shared__ float s_mel[4][N_MELS]; // staged mel columns (prologue only)
  __shared__ float s_out[4][1060];   // swizzle-padded: idx = f + (f>>5)

  const int tid = threadIdx.x;
  const int w   = tid >> 6;        // wave 0..3 -> row t0+w
  const int l   = tid & 63;
  // XCD swizzle for grid 1024: XCD x covers flats [x*128, x*128+128) -> L2
  // locality for melspec slice + adjacent output granules merge in L2.
  const int flat = (blockIdx.x & 7) * 128 + (blockIdx.x >> 3);
  const int b   = flat >> 8;          // 256 flats per batch
  const int t0  = (flat & 255) << 2;  // block covers t0..t0+3
  const int tA  = t0 + w;

  // ---- stage mel columns: s_mel[r][m] = mel[b][m][t0+r] ----
  for (int i = tid; i < 4 * N_MELS; i += 256) {
    const int m = i >> 2, r = i & 3;
    s_mel[r][m] = melspec[((size_t)b * N_MELS + m) * TIME + t0 + r];
  }
  __syncthreads();

  const float SCALE = 16777216.0f;                 // 2^24 fixed point
  const float SC48  = 281474976710656.0f;          // 2^48 (cc domain)
  const float LRI48 = 5.2041704279304213e-19f;     // 0.3*2/(B*T) * 2^-48

  // per-lane static structure, f = 16*l + k  (f=1024: zero fb row -> copy)
  float rs[16], rb[16], rw0[16], rw1[16], cc[16];
  int rm[16];

  const float* srow = spec_init + (size_t)(b * TIME + tA) * N_STFT;
  const float* melW = &s_mel[w][0];
#pragma unroll
  for (int k = 0; k < 16; ++k) {
    const int f = (l << 4) + k;
    rs[k] = srow[f];
    const int m = m0f[f];
    rm[k] = m;
    const float w0 = w0a[f], w1 = w1a[f];
    rw0[k] = w0 * SCALE;
    rw1[k] = w1 * SCALE;
    cc[k] = -SC48 * fmaf(melW[m], w0, melW[m + 1] * w1);  // -(mel.w)*2^48
    rb[k] = 0.f;
  }
  const float rt = (l == 63) ? srow[1024] : 0.f;

  // loop-invariant advance flags (m0 monotone, step <= 1 per bin)
  bool adv[16];
  adv[0] = false;
#pragma unroll
  for (int k = 1; k < 16; ++k) adv[k] = (rm[k] != rm[k - 1]);

  u32* __restrict__ Pw = &s_P[w][0];
  ((u64*)Pw)[l] = 0ULL;              // one ds_write_b64 zeroes 2 bins/lane
  // wave-private P: no block barrier anywhere in the hot loop

  // ---- PHASE STAGGER: break the 4-wave lockstep convoy on each SIMD ----
  // (waves on a SIMD are wave-w of 4 co-resident blocks; offset by block
  //  and w. 192cy per step ~= quarter of the ~780cy per-iter issue time.)
  {
    const int phase = ((blockIdx.x >> 3) + w) & 3;
    for (int i = 0; i < phase; ++i) __builtin_amdgcn_s_sleep(3);
  }

  for (int it = 0; it < MAX_ITER; ++it) {
    // ---- forward: run-compacted scatter (native ds_add_u32) ----
    {
      float a0 = rs[0] * rw0[0], a1 = rs[0] * rw1[0];
#pragma unroll
      for (int k = 1; k < 16; ++k) {
        if (adv[k]) atomicAdd(&Pw[rm[k - 1]], (u32)(a0 + 0.5f));
        const float n0 = (adv[k] ? a1 : a0) + rs[k] * rw0[k];
        a1 = (adv[k] ? 0.f : a1) + rs[k] * rw1[k];
        a0 = n0;
      }
      atomicAdd(&Pw[rm[15]],     (u32)(a0 + 0.5f));
      atomicAdd(&Pw[rm[15] + 1], (u32)(a1 + 0.5f));
    }
    __builtin_amdgcn_wave_barrier();   // scheduling fence only
    // ---- backward: unconditional ds_read2_b32 per k, all k independent ----
#pragma unroll
    for (int k = 0; k < 16; ++k) {
      const float p0 = (float)(int)Pw[rm[k]];      // ds_read2_b32 pair
      const float p1 = (float)(int)Pw[rm[k] + 1];
      const float g  = fmaf(p1, rw1[k], fmaf(p0, rw0[k], cc[k]));
      rb[k] = fmaf(0.9f, rb[k], g);
      rs[k] = fmaxf(fmaf(-LRI48, rb[k], rs[k]), 0.f);
    }
    __builtin_amdgcn_wave_barrier();
    // ---- zero P for next iteration (same-wave DS program order) ----
    ((u64*)Pw)[l] = 0ULL;
    __builtin_amdgcn_wave_barrier();
  }

  // ---- epilogue: transpose (f-major regs) -> (B, F, T) via swizzled LDS ----
#pragma unroll
  for (int k = 0; k < 16; ++k) {
    const int f = (l << 4) + k;
    s_out[w][f + (f >> 5)] = rs[k];
  }
  if (l == 63) s_out[w][1056] = rt;    // f=1024 -> 1024 + (1024>>5)
  __syncthreads();

  const int tl = tid & 3;    // t offset within the block's 4 rows
  const int fg = tid >> 2;   // 64 f phases
  float* obase = out + (size_t)b * N_STFT * TIME + t0 + tl;
  for (int f = fg; f < N_STFT; f += 64) {
    obase[(size_t)f * TIME] = s_out[tl][f + (f >> 5)];
  }
}

// ---------------- host-side fb structure (replaces imel_prep) -------------
static unsigned char g_tab[15360];
static bool g_tab_ready = false;

static float host_fbval(double freq, const double* f_pts, int m) {
  const double down = (freq - f_pts[m]) / (f_pts[m + 1] - f_pts[m]);
  const double up = (f_pts[m + 2] - freq) / (f_pts[m + 2] - f_pts[m + 1]);
  double v = down < up ? down : up;
  if (v < 0.0) v = 0.0;
  return (float)v;
}

static void build_tab() {
  double f_pts[130];
  const double m_max = 2595.0 * log10(1.0 + 8000.0 / 700.0);
  for (int i = 0; i < 130; ++i) {
    const double m = (double)i * m_max / 129.0;   // linspace(0, m_max, 130)
    f_pts[i] = 700.0 * (pow(10.0, m / 2595.0) - 1.0);
  }
  int* m0f = (int*)g_tab;
  float* w0a = (float*)(g_tab + 5120);
  float* w1a = (float*)(g_tab + 10240);
  for (int f = 0; f < N_STFT; ++f) {
    const double freq = (double)f * (8000.0 / 1024.0);
    int m0 = 0;                      // all-zero rows (f=0, f=1024) -> 0
    for (int m = 0; m < N_MELS; ++m) {
      if (host_fbval(freq, f_pts, m) != 0.0f) { m0 = m; break; }
    }
    if (m0 > N_MELS - 2) m0 = N_MELS - 2;  // keep (m0, m0+1) in range
    m0f[f] = m0;
    w0a[f] = host_fbval(freq, f_pts, m0);
    w1a[f] = host_fbval(freq, f_pts, m0 + 1);
  }
}

extern "C" void kernel_launch(void* const* d_in, const int* in_sizes, int n_in,
                              void* d_out, int out_size, void* d_ws, size_t ws_size,
                              hipStream_t stream) {
  const float* melspec = (const float*)d_in[0];
  const float* spec_init = (const float*)d_in[1];
  float* out = (float*)d_out;

  if (!g_tab_ready) { build_tab(); g_tab_ready = true; }

  int* m0f = (int*)d_ws;                          // 1025 ints
  float* w0a = (float*)((char*)d_ws + 5120);      // 1025 floats
  float* w1a = (float*)((char*)d_ws + 10240);     // 1025 floats

  hipMemcpyAsync(d_ws, g_tab, sizeof(g_tab), hipMemcpyHostToDevice, stream);
  imel_main<<<dim3(1024), dim3(256), 0, stream>>>(melspec, spec_init, m0f, w0a, w1a, out);
}